// Round 8
// baseline (310.544 us; speedup 1.0000x reference)
//
#include <hip/hip_runtime.h>
#include <hip/hip_bf16.h>

#define N_NODES 50000
#define N_EDGES 800000
#define D 128
#define BN_EPS 1e-5f
#define GEMM_ROWS 128
#define LDS_PITCH 136                          // 128 + 8 bf16 pad

#define BSH 8                                  // bucket = dst >> 8
#define NB 196                                 // ceil(50000/256) buckets
#define TILE 4096                              // edges per tile
#define NTILES ((N_EDGES + TILE - 1) / TILE)   // 196
#define REC_CAP 6144                           // max records/bucket (mean 4082, sigma 64)

typedef unsigned short u16;
typedef short bf16x8 __attribute__((ext_vector_type(8)));
typedef float f32x4  __attribute__((ext_vector_type(4)));

__device__ __forceinline__ u16 f2bf(float f) {
    union { float f; unsigned int u; } v; v.f = f;
    unsigned int u = v.u;
    return (u16)((u + 0x7FFF + ((u >> 16) & 1)) >> 16);   // RNE
}
__device__ __forceinline__ float bflo(unsigned int u) {
    union { unsigned int u; float f; } v; v.u = u << 16; return v.f;
}
__device__ __forceinline__ float bfhi(unsigned int u) {
    union { unsigned int u; float f; } v; v.u = u & 0xFFFF0000u; return v.f;
}
__device__ __forceinline__ unsigned int packbf(float a, float b) {
    return (unsigned int)f2bf(a) | ((unsigned int)f2bf(b) << 16);
}

// ---------------------------------------------------------------------------
// kernel 1: per-tile bucket histograms (blocks 0..195) + w_prep (blocks 196..323)
// block 196 also zeros both BN sums banks.
__global__ __launch_bounds__(256) void hist_prep(const int* __restrict__ dst,
                                                 const float* __restrict__ W1,
                                                 const float* __restrict__ W2,
                                                 int* __restrict__ thist,
                                                 u16* __restrict__ Wt1,
                                                 u16* __restrict__ Wt2,
                                                 float* __restrict__ sums) {
    __shared__ int h[256];
    const int t = threadIdx.x;
    const int b = blockIdx.x;
    if (b < NTILES) {
        h[t] = 0;
        __syncthreads();
        const int e0 = b * TILE;
#pragma unroll
        for (int i = 0; i < 16; ++i) {
            int e = e0 + t + 256 * i;
            if (e < N_EDGES) atomicAdd(&h[dst[e] >> BSH], 1);
        }
        __syncthreads();
        thist[b * 256 + t] = h[t];          // all 256 entries written (clears poison)
    } else {
        const int wb = b - NTILES;          // 0..127
        if (wb == 0) { sums[t] = 0.f; sums[256 + t] = 0.f; }
        int u = wb * 256 + t;               // 0..32767
        const float* W = (u < 16384) ? W1 : W2;
        u16* Wt        = (u < 16384) ? Wt1 : Wt2;
        int v = u & 16383;
        int k = v >> 7, n = v & 127;
        Wt[n * 128 + k] = f2bf(W[v]);       // Wt[n][k] = bf16(W[k][n])
    }
}

// kernel 2: reduce tile histograms -> btot, exclusive scan -> bbase/bcur (1 block)
__global__ __launch_bounds__(256) void bucket_scan(const int* __restrict__ thist,
                                                   int* __restrict__ btot,
                                                   int* __restrict__ bbase,
                                                   int* __restrict__ bcur,
                                                   int* __restrict__ row_ptr) {
    __shared__ int s[256];
    const int t = threadIdx.x;
    int v = 0;
    for (int i = 0; i < NTILES; ++i) v += thist[i * 256 + t];
    s[t] = v;
    __syncthreads();
#pragma unroll
    for (int off = 1; off < 256; off <<= 1) {
        int add = (t >= off) ? s[t - off] : 0;
        __syncthreads();
        s[t] += add;
        __syncthreads();
    }
    if (t < NB) { btot[t] = v; bbase[t] = s[t] - v; bcur[t] = s[t] - v; }
    if (t == 0) row_ptr[N_NODES] = N_EDGES;
}

// kernel 3: bin edges into bucket-contiguous records via LDS staging.
// record = src (u16 low) | (dst&255)<<16
__global__ __launch_bounds__(256) void bucket_scatter(const int* __restrict__ src,
                                                      const int* __restrict__ dst,
                                                      int* __restrict__ bcur,
                                                      unsigned int* __restrict__ brec) {
    __shared__ int h[256];
    __shared__ int sb[256];
    __shared__ int lbase[256];
    __shared__ int lcur[256];
    __shared__ int gbase[256];
    __shared__ unsigned int  rec[TILE];
    __shared__ unsigned char rbk[TILE];
    const int t  = threadIdx.x;
    const int e0 = blockIdx.x * TILE;
    const int tcount = min(TILE, N_EDGES - e0);

    h[t] = 0;
    __syncthreads();

    unsigned int myrec[16];
    int          myb[16];
#pragma unroll
    for (int i = 0; i < 16; ++i) {
        int e = e0 + t + 256 * i;
        if (e < N_EDGES) {
            unsigned int s_ = (unsigned int)src[e];
            unsigned int d_ = (unsigned int)dst[e];
            int b = (int)(d_ >> BSH);
            myb[i]   = b;
            myrec[i] = s_ | ((d_ & 255u) << 16);
            atomicAdd(&h[b], 1);
        } else myb[i] = -1;
    }
    __syncthreads();
    sb[t] = h[t];
    __syncthreads();
#pragma unroll
    for (int off = 1; off < 256; off <<= 1) {
        int add = (t >= off) ? sb[t - off] : 0;
        __syncthreads();
        sb[t] += add;
        __syncthreads();
    }
    lbase[t] = sb[t] - h[t];
    lcur[t]  = sb[t] - h[t];
    __syncthreads();
#pragma unroll
    for (int i = 0; i < 16; ++i) {
        if (myb[i] >= 0) {
            int p = atomicAdd(&lcur[myb[i]], 1);
            rec[p] = myrec[i];
            rbk[p] = (unsigned char)myb[i];
        }
    }
    __syncthreads();
    if (t < NB && h[t] > 0) gbase[t] = atomicAdd(&bcur[t], h[t]);
    __syncthreads();
    for (int i = t; i < tcount; i += 256) {
        int b = rbk[i];
        brec[gbase[b] + (i - lbase[b])] = rec[i];
    }
}

// kernel 4: per-bucket counting sort -> row_ptr, dinv, col (u16), coalesced
__global__ __launch_bounds__(256) void bucket_csr(const unsigned int* __restrict__ brec,
                                                  const int* __restrict__ bbase,
                                                  const int* __restrict__ btot,
                                                  int* __restrict__ row_ptr,
                                                  u16* __restrict__ col,
                                                  float* __restrict__ dinv) {
    __shared__ unsigned int rec[REC_CAP];
    __shared__ u16 cls[REC_CAP];
    __shared__ int h[256];
    __shared__ int sb[256];
    __shared__ int lcur[256];
    const int b    = blockIdx.x;
    const int t    = threadIdx.x;
    const int base = bbase[b];
    const int cnt  = min(btot[b], REC_CAP);
    const int n0   = b << BSH;
    const int nn   = min(256, N_NODES - n0);

    for (int i = t; i < cnt; i += 256) rec[i] = brec[base + i];
    h[t] = 0;
    __syncthreads();
    for (int i = t; i < cnt; i += 256) atomicAdd(&h[(rec[i] >> 16) & 255u], 1);
    __syncthreads();
    sb[t] = h[t];
    __syncthreads();
#pragma unroll
    for (int off = 1; off < 256; off <<= 1) {
        int add = (t >= off) ? sb[t - off] : 0;
        __syncthreads();
        sb[t] += add;
        __syncthreads();
    }
    int excl = sb[t] - h[t];
    lcur[t] = excl;
    if (t < nn) {
        row_ptr[n0 + t] = base + excl;
        dinv[n0 + t]    = rsqrtf((float)h[t] + 1.0f);
    }
    __syncthreads();
    for (int i = t; i < cnt; i += 256) {
        unsigned int r = rec[i];
        int p = atomicAdd(&lcur[(r >> 16) & 255u], 1);
        cls[p] = (u16)(r & 0xFFFFu);
    }
    __syncthreads();
    for (int i = t; i < cnt; i += 256) col[base + i] = cls[i];
}

// ---------------------------------------------------------------------------
// C_bf16[N x 128] = act(X) @ W * dinv[row]  via bf16 MFMA (f32 acc).
// BN_IN=false: X is f32. BN_IN=true: X is bf16 and PReLU(BN(x)) applied in staging.
template <bool BN_IN>
__global__ __launch_bounds__(256) void gemm_bf16(const void* __restrict__ Xv,
                                                 const u16* __restrict__ Wt,
                                                 u16* __restrict__ C,
                                                 const float* __restrict__ dinv,
                                                 const float* __restrict__ sums,
                                                 const float* __restrict__ gamma,
                                                 const float* __restrict__ beta,
                                                 const float* __restrict__ a,
                                                 int nrows) {
    __shared__ u16 As[GEMM_ROWS * LDS_PITCH];   // 34816 B
    __shared__ u16 Ws[128 * LDS_PITCH];         // 34816 B
    const int tid  = threadIdx.x;
    const int row0 = blockIdx.x * GEMM_ROWS;
    const float invN = 1.0f / (float)N_NODES;

    const bf16x8* Wt8 = (const bf16x8*)Wt;
#pragma unroll
    for (int i = 0; i < 8; ++i) {
        int u = tid + 256 * i;
        int n = u >> 4, kg = u & 15;
        *(bf16x8*)&Ws[n * LDS_PITCH + kg * 8] = Wt8[u];
    }

    if (BN_IN) {
        const uint4* X4 = (const uint4*)Xv;
        const float av = a[0];
#pragma unroll
        for (int i = 0; i < 8; ++i) {
            int u    = tid + 256 * i;
            int r    = u >> 4, kg = u & 15;
            int grow = row0 + r;
            uint4 o = make_uint4(0, 0, 0, 0);
            if (grow < nrows) {
                uint4 v = X4[(size_t)grow * 16 + kg];
                float f[8] = { bflo(v.x), bfhi(v.x), bflo(v.y), bfhi(v.y),
                               bflo(v.z), bfhi(v.z), bflo(v.w), bfhi(v.w) };
#pragma unroll
                for (int c = 0; c < 8; ++c) {
                    int fe     = kg * 8 + c;
                    float mean = sums[fe] * invN;
                    float var  = sums[128 + fe] * invN - mean * mean;
                    float sc   = rsqrtf(var + BN_EPS) * gamma[fe];
                    float y    = (f[c] - mean) * sc + beta[fe];
                    f[c]       = (y >= 0.f) ? y : av * y;
                }
                o.x = packbf(f[0], f[1]); o.y = packbf(f[2], f[3]);
                o.z = packbf(f[4], f[5]); o.w = packbf(f[6], f[7]);
            }
            *(uint4*)&As[r * LDS_PITCH + kg * 8] = o;
        }
    } else {
        const float4* X4 = (const float4*)Xv;
#pragma unroll
        for (int i = 0; i < 16; ++i) {
            int u    = tid + 256 * i;
            int r    = u >> 5, kf = u & 31;
            int grow = row0 + r;
            float4 v = make_float4(0.f, 0.f, 0.f, 0.f);
            if (grow < nrows) v = X4[(size_t)grow * 32 + kf];
            ushort4 p;
            p.x = f2bf(v.x); p.y = f2bf(v.y); p.z = f2bf(v.z); p.w = f2bf(v.w);
            *(ushort4*)&As[r * LDS_PITCH + kf * 4] = p;
        }
    }
    __syncthreads();

    const int wv   = tid >> 6;
    const int lane = tid & 63;
    const int n    = lane & 15;
    const int q    = lane >> 4;
    const int c0   = wv * 32;

    bf16x8 bfr[4][2];
#pragma unroll
    for (int kb = 0; kb < 4; ++kb)
#pragma unroll
        for (int c = 0; c < 2; ++c)
            bfr[kb][c] = *(const bf16x8*)&Ws[(c0 + 16 * c + n) * LDS_PITCH + 32 * kb + 8 * q];

    f32x4 acc[8][2];
    const f32x4 z = {0.f, 0.f, 0.f, 0.f};
#pragma unroll
    for (int rt = 0; rt < 8; ++rt) { acc[rt][0] = z; acc[rt][1] = z; }

#pragma unroll
    for (int kb = 0; kb < 4; ++kb) {
#pragma unroll
        for (int rt = 0; rt < 8; ++rt) {
            bf16x8 af = *(const bf16x8*)&As[(16 * rt + n) * LDS_PITCH + 32 * kb + 8 * q];
            acc[rt][0] = __builtin_amdgcn_mfma_f32_16x16x32_bf16(af, bfr[kb][0], acc[rt][0], 0, 0, 0);
            acc[rt][1] = __builtin_amdgcn_mfma_f32_16x16x32_bf16(af, bfr[kb][1], acc[rt][1], 0, 0, 0);
        }
    }

#pragma unroll
    for (int rt = 0; rt < 8; ++rt) {
        int gr0 = row0 + 16 * rt + 4 * q;
#pragma unroll
        for (int r = 0; r < 4; ++r) {
            int gr = gr0 + r;
            if (gr < nrows) {
                float dv = dinv[gr];
                C[(size_t)gr * D + c0 + n]      = f2bf(acc[rt][0][r] * dv);
                C[(size_t)gr * D + c0 + 16 + n] = f2bf(acc[rt][1][r] * dv);
            }
        }
    }
}

// ---------------------------------------------------------------------------
// pull-aggregate (bf16 in/out, f32 acc) with fused BN sum/sumsq reduction.
// out[d] = dinv[d] * (Σ_{s in in(d)} H[s] + H[d]);  sums[f] += Σ out, sums[128+f] += Σ out².
// 16 lanes per node; lane sub covers features 8*sub..8*sub+7.
__global__ __launch_bounds__(256) void pull_agg_red(const u16* __restrict__ H,
                                                    const int* __restrict__ row_ptr,
                                                    const u16* __restrict__ col,
                                                    const float* __restrict__ dinv,
                                                    u16* __restrict__ out,
                                                    float* __restrict__ sums) {
    __shared__ float red[16 * 128];
    const int sub  = threadIdx.x & 15;
    const int g    = threadIdx.x >> 4;
    const int grp  = (blockIdx.x * blockDim.x + threadIdx.x) >> 4;
    const int ngrp = (gridDim.x * blockDim.x) >> 4;
    const uint4* H4   = (const uint4*)H;
    uint4*       out4 = (uint4*)out;

    float bs[8] = {}, bq[8] = {};

    for (int d = grp; d < N_NODES; d += ngrp) {
        const int beg = row_ptr[d];
        const int end = row_ptr[d + 1];
        float a0[8], a1[8] = {}, a2[8] = {}, a3[8] = {};
        {
            uint4 v = H4[(size_t)d * 16 + sub];          // self loop
            a0[0] = bflo(v.x); a0[1] = bfhi(v.x); a0[2] = bflo(v.y); a0[3] = bfhi(v.y);
            a0[4] = bflo(v.z); a0[5] = bfhi(v.z); a0[6] = bflo(v.w); a0[7] = bfhi(v.w);
        }
        int j = beg;
        for (; j + 3 < end; j += 4) {
            const int s0 = col[j], s1 = col[j + 1], s2 = col[j + 2], s3 = col[j + 3];
            const uint4 v0 = H4[(size_t)s0 * 16 + sub];
            const uint4 v1 = H4[(size_t)s1 * 16 + sub];
            const uint4 v2 = H4[(size_t)s2 * 16 + sub];
            const uint4 v3 = H4[(size_t)s3 * 16 + sub];
            a0[0] += bflo(v0.x); a0[1] += bfhi(v0.x); a0[2] += bflo(v0.y); a0[3] += bfhi(v0.y);
            a0[4] += bflo(v0.z); a0[5] += bfhi(v0.z); a0[6] += bflo(v0.w); a0[7] += bfhi(v0.w);
            a1[0] += bflo(v1.x); a1[1] += bfhi(v1.x); a1[2] += bflo(v1.y); a1[3] += bfhi(v1.y);
            a1[4] += bflo(v1.z); a1[5] += bfhi(v1.z); a1[6] += bflo(v1.w); a1[7] += bfhi(v1.w);
            a2[0] += bflo(v2.x); a2[1] += bfhi(v2.x); a2[2] += bflo(v2.y); a2[3] += bfhi(v2.y);
            a2[4] += bflo(v2.z); a2[5] += bfhi(v2.z); a2[6] += bflo(v2.w); a2[7] += bfhi(v2.w);
            a3[0] += bflo(v3.x); a3[1] += bfhi(v3.x); a3[2] += bflo(v3.y); a3[3] += bfhi(v3.y);
            a3[4] += bflo(v3.z); a3[5] += bfhi(v3.z); a3[6] += bflo(v3.w); a3[7] += bfhi(v3.w);
        }
        for (; j < end; ++j) {
            const uint4 v = H4[(size_t)col[j] * 16 + sub];
            a0[0] += bflo(v.x); a0[1] += bfhi(v.x); a0[2] += bflo(v.y); a0[3] += bfhi(v.y);
            a0[4] += bflo(v.z); a0[5] += bfhi(v.z); a0[6] += bflo(v.w); a0[7] += bfhi(v.w);
        }
        const float dv = dinv[d];
        float r[8];
#pragma unroll
        for (int c = 0; c < 8; ++c) {
            r[c] = ((a0[c] + a1[c]) + (a2[c] + a3[c])) * dv;
            bs[c] += r[c];
            bq[c] += r[c] * r[c];
        }
        uint4 o;
        o.x = packbf(r[0], r[1]); o.y = packbf(r[2], r[3]);
        o.z = packbf(r[4], r[5]); o.w = packbf(r[6], r[7]);
        out4[(size_t)d * 16 + sub] = o;
    }

    // block-level reduce of BN partials, then one atomic per feature per block
#pragma unroll
    for (int c = 0; c < 8; ++c) red[g * 128 + sub * 8 + c] = bs[c];
    __syncthreads();
    if (threadIdx.x < 128) {
        float acc = 0.f;
#pragma unroll
        for (int g2 = 0; g2 < 16; ++g2) acc += red[g2 * 128 + threadIdx.x];
        atomicAdd(&sums[threadIdx.x], acc);
    }
    __syncthreads();
#pragma unroll
    for (int c = 0; c < 8; ++c) red[g * 128 + sub * 8 + c] = bq[c];
    __syncthreads();
    if (threadIdx.x < 128) {
        float acc = 0.f;
#pragma unroll
        for (int g2 = 0; g2 < 16; ++g2) acc += red[g2 * 128 + threadIdx.x];
        atomicAdd(&sums[128 + threadIdx.x], acc);
    }
}

// ---------------------------------------------------------------------------
// BN + PReLU, bf16 in -> f32 out (final)
__global__ void bn_prelu_bf(const u16* __restrict__ X, const float* __restrict__ sums,
                            const float* __restrict__ gamma, const float* __restrict__ beta,
                            const float* __restrict__ a, float* __restrict__ out,
                            float invN) {
    int idx = blockIdx.x * blockDim.x + threadIdx.x;     // pair index
    if (idx >= N_NODES * 64) return;
    unsigned int u = ((const unsigned int*)X)[idx];
    int f0 = (idx * 2) & 127;
    float av = a[0];
    float2 o;
    {
        float mean = sums[f0] * invN;
        float var  = sums[128 + f0] * invN - mean * mean;
        float sc   = rsqrtf(var + BN_EPS) * gamma[f0];
        float y    = (bflo(u) - mean) * sc + beta[f0];
        o.x = (y >= 0.f) ? y : av * y;
    }
    {
        int f1 = f0 + 1;
        float mean = sums[f1] * invN;
        float var  = sums[128 + f1] * invN - mean * mean;
        float sc   = rsqrtf(var + BN_EPS) * gamma[f1];
        float y    = (bfhi(u) - mean) * sc + beta[f1];
        o.y = (y >= 0.f) ? y : av * y;
    }
    ((float2*)out)[idx] = o;
}

// ---------------------------------------------------------------------------
extern "C" void kernel_launch(void* const* d_in, const int* in_sizes, int n_in,
                              void* d_out, int out_size, void* d_ws, size_t ws_size,
                              hipStream_t stream) {
    const float* x      = (const float*)d_in[0];
    const int*   edges  = (const int*)d_in[1];   // [2, E]: src then dst
    const float* W1     = (const float*)d_in[2];
    // b1 = d_in[3] cancels under training-mode BN -> skipped
    const float* gamma1 = (const float*)d_in[4];
    const float* beta1  = (const float*)d_in[5];
    const float* a1     = (const float*)d_in[6];
    const float* W2     = (const float*)d_in[7];
    // b2 = d_in[8] skipped (same reason)
    const float* gamma2 = (const float*)d_in[9];
    const float* beta2  = (const float*)d_in[10];
    const float* a2     = (const float*)d_in[11];

    const int* src = edges;
    const int* dst = edges + N_EDGES;

    float* OUT = (float*)d_out;                      // final f32 output
    char* ws = (char*)d_ws;
    u16*   Abf      = (u16*)ws;    ws += (size_t)N_NODES * D * sizeof(u16);   // 12.8 MB
    u16*   Obf      = (u16*)ws;    ws += (size_t)N_NODES * D * sizeof(u16);   // 12.8 MB
    float* dinv     = (float*)ws;  ws += N_NODES * sizeof(float);
    float* sums     = (float*)ws;  ws += 512 * sizeof(float);   // [0..255]=layer1, [256..511]=layer2
    int*   row_ptr  = (int*)ws;    ws += (N_NODES + 1) * sizeof(int);
    int*   btot     = (int*)ws;    ws += NB * sizeof(int);
    int*   bbase    = (int*)ws;    ws += NB * sizeof(int);
    int*   bcur     = (int*)ws;    ws += NB * sizeof(int);
    int*   thist    = (int*)ws;    ws += (size_t)NTILES * 256 * sizeof(int);  // 200 KB
    unsigned int* brec = (unsigned int*)ws; ws += (size_t)N_EDGES * sizeof(unsigned int);
    u16*   col      = (u16*)ws;    ws += (size_t)N_EDGES * sizeof(u16);
    u16*   Wt1      = (u16*)ws;    ws += 16384 * sizeof(u16);
    u16*   Wt2      = (u16*)ws;    ws += 16384 * sizeof(u16);

    const float invN = 1.0f / (float)N_NODES;
    const int gemmGrid = (N_NODES + GEMM_ROWS - 1) / GEMM_ROWS;   // 391
    const int prGrid   = (N_NODES * 64 + 255) / 256;              // 12500

    // --- CSR build + weight prep + sums zero (9 dispatches total) ---
    hist_prep<<<NTILES + 128, 256, 0, stream>>>(dst, W1, W2, thist, Wt1, Wt2, sums);
    bucket_scan<<<1, 256, 0, stream>>>(thist, btot, bbase, bcur, row_ptr);
    bucket_scatter<<<NTILES, 256, 0, stream>>>(src, dst, bcur, brec);
    bucket_csr<<<NB, 256, 0, stream>>>(brec, bbase, btot, row_ptr, col, dinv);

    // --- layer 1 ---
    gemm_bf16<false><<<gemmGrid, 256, 0, stream>>>(x, Wt1, Abf, dinv,
                                                   nullptr, nullptr, nullptr, nullptr, N_NODES);
    pull_agg_red<<<2048, 256, 0, stream>>>(Abf, row_ptr, col, dinv, Obf, sums);

    // --- layer 2 (BN1+PReLU fused into GEMM2 staging) ---
    gemm_bf16<true><<<gemmGrid, 256, 0, stream>>>(Obf, Wt2, Abf, dinv,
                                                  sums, gamma1, beta1, a1, N_NODES);
    pull_agg_red<<<2048, 256, 0, stream>>>(Abf, row_ptr, col, dinv, Obf, sums + 256);
    bn_prelu_bf<<<prGrid, 256, 0, stream>>>(Obf, sums + 256, gamma2, beta2, a2, OUT, invN);
}

// Round 9
// 304.163 us; speedup vs baseline: 1.0210x; 1.0210x over previous
//
#include <hip/hip_runtime.h>
#include <hip/hip_bf16.h>

#define N_NODES 50000
#define N_EDGES 800000
#define D 128
#define BN_EPS 1e-5f
#define GEMM_ROWS 128
#define LDS_PITCH 136                          // 128 + 8 bf16 pad

#define BSH 8                                  // bucket = dst >> 8
#define NB 196                                 // ceil(50000/256) buckets
#define TILE 4096                              // edges per tile
#define NTILES ((N_EDGES + TILE - 1) / TILE)   // 196
#define REC_CAP 6144                           // max records/bucket (mean 4082, sigma 64)

typedef unsigned short u16;
typedef short bf16x8 __attribute__((ext_vector_type(8)));
typedef float f32x4  __attribute__((ext_vector_type(4)));

__device__ __forceinline__ u16 f2bf(float f) {
    union { float f; unsigned int u; } v; v.f = f;
    unsigned int u = v.u;
    return (u16)((u + 0x7FFF + ((u >> 16) & 1)) >> 16);   // RNE
}
__device__ __forceinline__ float bflo(unsigned int u) {
    union { unsigned int u; float f; } v; v.u = u << 16; return v.f;
}
__device__ __forceinline__ float bfhi(unsigned int u) {
    union { unsigned int u; float f; } v; v.u = u & 0xFFFF0000u; return v.f;
}
__device__ __forceinline__ unsigned int packbf(float a, float b) {
    return (unsigned int)f2bf(a) | ((unsigned int)f2bf(b) << 16);
}

// ---------------------------------------------------------------------------
// kernel 1: per-tile bucket histograms (blocks 0..195) + w_prep (blocks 196..323)
// block 196 also zeros both BN sums banks (layer1 + layer2).
__global__ __launch_bounds__(256) void hist_prep(const int* __restrict__ dst,
                                                 const float* __restrict__ W1,
                                                 const float* __restrict__ W2,
                                                 int* __restrict__ thist,
                                                 u16* __restrict__ Wt1,
                                                 u16* __restrict__ Wt2,
                                                 float* __restrict__ sums) {
    __shared__ int h[256];
    const int t = threadIdx.x;
    const int b = blockIdx.x;
    if (b < NTILES) {
        h[t] = 0;
        __syncthreads();
        const int e0 = b * TILE;
#pragma unroll
        for (int i = 0; i < 16; ++i) {
            int e = e0 + t + 256 * i;
            if (e < N_EDGES) atomicAdd(&h[dst[e] >> BSH], 1);
        }
        __syncthreads();
        thist[b * 256 + t] = h[t];          // all 256 entries written
    } else {
        const int wb = b - NTILES;          // 0..127
        if (wb == 0) { sums[t] = 0.f; sums[256 + t] = 0.f; }
        int u = wb * 256 + t;               // 0..32767
        const float* W = (u < 16384) ? W1 : W2;
        u16* Wt        = (u < 16384) ? Wt1 : Wt2;
        int v = u & 16383;
        int k = v >> 7, n = v & 127;
        Wt[n * 128 + k] = f2bf(W[v]);       // Wt[n][k] = bf16(W[k][n])
    }
}

// kernel 2: reduce tile histograms -> btot, exclusive scan -> bbase/bcur (1 block)
__global__ __launch_bounds__(256) void bucket_scan(const int* __restrict__ thist,
                                                   int* __restrict__ btot,
                                                   int* __restrict__ bbase,
                                                   int* __restrict__ bcur,
                                                   int* __restrict__ row_ptr) {
    __shared__ int s[256];
    const int t = threadIdx.x;
    int v = 0;
    for (int i = 0; i < NTILES; ++i) v += thist[i * 256 + t];
    s[t] = v;
    __syncthreads();
#pragma unroll
    for (int off = 1; off < 256; off <<= 1) {
        int add = (t >= off) ? s[t - off] : 0;
        __syncthreads();
        s[t] += add;
        __syncthreads();
    }
    if (t < NB) { btot[t] = v; bbase[t] = s[t] - v; bcur[t] = s[t] - v; }
    if (t == 0) row_ptr[N_NODES] = N_EDGES;
}

// kernel 3: bin edges into bucket-contiguous records via LDS staging.
// record = src (u16 low) | (dst&255)<<16
__global__ __launch_bounds__(256) void bucket_scatter(const int* __restrict__ src,
                                                      const int* __restrict__ dst,
                                                      int* __restrict__ bcur,
                                                      unsigned int* __restrict__ brec) {
    __shared__ int h[256];
    __shared__ int sb[256];
    __shared__ int lbase[256];
    __shared__ int lcur[256];
    __shared__ int gbase[256];
    __shared__ unsigned int  rec[TILE];
    __shared__ unsigned char rbk[TILE];
    const int t  = threadIdx.x;
    const int e0 = blockIdx.x * TILE;
    const int tcount = min(TILE, N_EDGES - e0);

    h[t] = 0;
    __syncthreads();

    unsigned int myrec[16];
    int          myb[16];
#pragma unroll
    for (int i = 0; i < 16; ++i) {
        int e = e0 + t + 256 * i;
        if (e < N_EDGES) {
            unsigned int s_ = (unsigned int)src[e];
            unsigned int d_ = (unsigned int)dst[e];
            int b = (int)(d_ >> BSH);
            myb[i]   = b;
            myrec[i] = s_ | ((d_ & 255u) << 16);
            atomicAdd(&h[b], 1);
        } else myb[i] = -1;
    }
    __syncthreads();
    sb[t] = h[t];
    __syncthreads();
#pragma unroll
    for (int off = 1; off < 256; off <<= 1) {
        int add = (t >= off) ? sb[t - off] : 0;
        __syncthreads();
        sb[t] += add;
        __syncthreads();
    }
    lbase[t] = sb[t] - h[t];
    lcur[t]  = sb[t] - h[t];
    __syncthreads();
#pragma unroll
    for (int i = 0; i < 16; ++i) {
        if (myb[i] >= 0) {
            int p = atomicAdd(&lcur[myb[i]], 1);
            rec[p] = myrec[i];
            rbk[p] = (unsigned char)myb[i];
        }
    }
    __syncthreads();
    if (t < NB && h[t] > 0) gbase[t] = atomicAdd(&bcur[t], h[t]);
    __syncthreads();
    for (int i = t; i < tcount; i += 256) {
        int b = rbk[i];
        brec[gbase[b] + (i - lbase[b])] = rec[i];
    }
}

// kernel 4: per-bucket counting sort -> row_ptr, dinv, col (u16), coalesced
__global__ __launch_bounds__(256) void bucket_csr(const unsigned int* __restrict__ brec,
                                                  const int* __restrict__ bbase,
                                                  const int* __restrict__ btot,
                                                  int* __restrict__ row_ptr,
                                                  u16* __restrict__ col,
                                                  float* __restrict__ dinv) {
    __shared__ unsigned int rec[REC_CAP];
    __shared__ u16 cls[REC_CAP];
    __shared__ int h[256];
    __shared__ int sb[256];
    __shared__ int lcur[256];
    const int b    = blockIdx.x;
    const int t    = threadIdx.x;
    const int base = bbase[b];
    const int cnt  = min(btot[b], REC_CAP);
    const int n0   = b << BSH;
    const int nn   = min(256, N_NODES - n0);

    for (int i = t; i < cnt; i += 256) rec[i] = brec[base + i];
    h[t] = 0;
    __syncthreads();
    for (int i = t; i < cnt; i += 256) atomicAdd(&h[(rec[i] >> 16) & 255u], 1);
    __syncthreads();
    sb[t] = h[t];
    __syncthreads();
#pragma unroll
    for (int off = 1; off < 256; off <<= 1) {
        int add = (t >= off) ? sb[t - off] : 0;
        __syncthreads();
        sb[t] += add;
        __syncthreads();
    }
    int excl = sb[t] - h[t];
    lcur[t] = excl;
    if (t < nn) {
        row_ptr[n0 + t] = base + excl;
        dinv[n0 + t]    = rsqrtf((float)h[t] + 1.0f);
    }
    __syncthreads();
    for (int i = t; i < cnt; i += 256) {
        unsigned int r = rec[i];
        int p = atomicAdd(&lcur[(r >> 16) & 255u], 1);
        cls[p] = (u16)(r & 0xFFFFu);
    }
    __syncthreads();
    for (int i = t; i < cnt; i += 256) col[base + i] = cls[i];
}

// ---------------------------------------------------------------------------
// C_bf16[N x 128] = act(X) @ W * dinv[row]  via bf16 MFMA (f32 acc).
// BN_IN=false: X is f32. BN_IN=true: X is bf16 and PReLU(BN(x)) applied in staging.
template <bool BN_IN>
__global__ __launch_bounds__(256) void gemm_bf16(const void* __restrict__ Xv,
                                                 const u16* __restrict__ Wt,
                                                 u16* __restrict__ C,
                                                 const float* __restrict__ dinv,
                                                 const float* __restrict__ sums,
                                                 const float* __restrict__ gamma,
                                                 const float* __restrict__ beta,
                                                 const float* __restrict__ a,
                                                 int nrows) {
    __shared__ u16 As[GEMM_ROWS * LDS_PITCH];   // 34816 B
    __shared__ u16 Ws[128 * LDS_PITCH];         // 34816 B
    const int tid  = threadIdx.x;
    const int row0 = blockIdx.x * GEMM_ROWS;
    const float invN = 1.0f / (float)N_NODES;

    const bf16x8* Wt8 = (const bf16x8*)Wt;
#pragma unroll
    for (int i = 0; i < 8; ++i) {
        int u = tid + 256 * i;
        int n = u >> 4, kg = u & 15;
        *(bf16x8*)&Ws[n * LDS_PITCH + kg * 8] = Wt8[u];
    }

    if (BN_IN) {
        const uint4* X4 = (const uint4*)Xv;
        const float av = a[0];
#pragma unroll
        for (int i = 0; i < 8; ++i) {
            int u    = tid + 256 * i;
            int r    = u >> 4, kg = u & 15;
            int grow = row0 + r;
            uint4 o = make_uint4(0, 0, 0, 0);
            if (grow < nrows) {
                uint4 v = X4[(size_t)grow * 16 + kg];
                float f[8] = { bflo(v.x), bfhi(v.x), bflo(v.y), bfhi(v.y),
                               bflo(v.z), bfhi(v.z), bflo(v.w), bfhi(v.w) };
#pragma unroll
                for (int c = 0; c < 8; ++c) {
                    int fe     = kg * 8 + c;
                    float mean = sums[fe] * invN;
                    float var  = sums[128 + fe] * invN - mean * mean;
                    float sc   = rsqrtf(var + BN_EPS) * gamma[fe];
                    float y    = (f[c] - mean) * sc + beta[fe];
                    f[c]       = (y >= 0.f) ? y : av * y;
                }
                o.x = packbf(f[0], f[1]); o.y = packbf(f[2], f[3]);
                o.z = packbf(f[4], f[5]); o.w = packbf(f[6], f[7]);
            }
            *(uint4*)&As[r * LDS_PITCH + kg * 8] = o;
        }
    } else {
        const float4* X4 = (const float4*)Xv;
#pragma unroll
        for (int i = 0; i < 16; ++i) {
            int u    = tid + 256 * i;
            int r    = u >> 5, kf = u & 31;
            int grow = row0 + r;
            float4 v = make_float4(0.f, 0.f, 0.f, 0.f);
            if (grow < nrows) v = X4[(size_t)grow * 32 + kf];
            ushort4 p;
            p.x = f2bf(v.x); p.y = f2bf(v.y); p.z = f2bf(v.z); p.w = f2bf(v.w);
            *(ushort4*)&As[r * LDS_PITCH + kf * 4] = p;
        }
    }
    __syncthreads();

    const int wv   = tid >> 6;
    const int lane = tid & 63;
    const int n    = lane & 15;
    const int q    = lane >> 4;
    const int c0   = wv * 32;

    bf16x8 bfr[4][2];
#pragma unroll
    for (int kb = 0; kb < 4; ++kb)
#pragma unroll
        for (int c = 0; c < 2; ++c)
            bfr[kb][c] = *(const bf16x8*)&Ws[(c0 + 16 * c + n) * LDS_PITCH + 32 * kb + 8 * q];

    f32x4 acc[8][2];
    const f32x4 z = {0.f, 0.f, 0.f, 0.f};
#pragma unroll
    for (int rt = 0; rt < 8; ++rt) { acc[rt][0] = z; acc[rt][1] = z; }

#pragma unroll
    for (int kb = 0; kb < 4; ++kb) {
#pragma unroll
        for (int rt = 0; rt < 8; ++rt) {
            bf16x8 af = *(const bf16x8*)&As[(16 * rt + n) * LDS_PITCH + 32 * kb + 8 * q];
            acc[rt][0] = __builtin_amdgcn_mfma_f32_16x16x32_bf16(af, bfr[kb][0], acc[rt][0], 0, 0, 0);
            acc[rt][1] = __builtin_amdgcn_mfma_f32_16x16x32_bf16(af, bfr[kb][1], acc[rt][1], 0, 0, 0);
        }
    }

#pragma unroll
    for (int rt = 0; rt < 8; ++rt) {
        int gr0 = row0 + 16 * rt + 4 * q;
#pragma unroll
        for (int r = 0; r < 4; ++r) {
            int gr = gr0 + r;
            if (gr < nrows) {
                float dv = dinv[gr];
                C[(size_t)gr * D + c0 + n]      = f2bf(acc[rt][0][r] * dv);
                C[(size_t)gr * D + c0 + 16 + n] = f2bf(acc[rt][1][r] * dv);
            }
        }
    }
}

// ---------------------------------------------------------------------------
// pull-aggregate (bf16 in / bf16 out, f32 accumulate), lean R7 shape:
// out[d] = dinv[d] * (Σ_{s in in(d)} H[s] + H[d])
// 16 lanes per node; lane sub covers features 8*sub..8*sub+7 via one uint4.
__global__ __launch_bounds__(256) void pull_agg(const u16* __restrict__ H,
                                                const int* __restrict__ row_ptr,
                                                const u16* __restrict__ col,
                                                const float* __restrict__ dinv,
                                                u16* __restrict__ out) {
    const int sub  = threadIdx.x & 15;
    const int grp  = (blockIdx.x * blockDim.x + threadIdx.x) >> 4;
    const int ngrp = (gridDim.x * blockDim.x) >> 4;
    const uint4* H4   = (const uint4*)H;
    uint4*       out4 = (uint4*)out;

    for (int d = grp; d < N_NODES; d += ngrp) {
        const int beg = row_ptr[d];
        const int end = row_ptr[d + 1];
        float a0[8], a1[8] = {}, a2[8] = {}, a3[8] = {};
        {
            uint4 v = H4[(size_t)d * 16 + sub];          // self loop
            a0[0] = bflo(v.x); a0[1] = bfhi(v.x); a0[2] = bflo(v.y); a0[3] = bfhi(v.y);
            a0[4] = bflo(v.z); a0[5] = bfhi(v.z); a0[6] = bflo(v.w); a0[7] = bfhi(v.w);
        }
        int j = beg;
        for (; j + 3 < end; j += 4) {
            const int s0 = col[j], s1 = col[j + 1], s2 = col[j + 2], s3 = col[j + 3];
            const uint4 v0 = H4[(size_t)s0 * 16 + sub];
            const uint4 v1 = H4[(size_t)s1 * 16 + sub];
            const uint4 v2 = H4[(size_t)s2 * 16 + sub];
            const uint4 v3 = H4[(size_t)s3 * 16 + sub];
            a0[0] += bflo(v0.x); a0[1] += bfhi(v0.x); a0[2] += bflo(v0.y); a0[3] += bfhi(v0.y);
            a0[4] += bflo(v0.z); a0[5] += bfhi(v0.z); a0[6] += bflo(v0.w); a0[7] += bfhi(v0.w);
            a1[0] += bflo(v1.x); a1[1] += bfhi(v1.x); a1[2] += bflo(v1.y); a1[3] += bfhi(v1.y);
            a1[4] += bflo(v1.z); a1[5] += bfhi(v1.z); a1[6] += bflo(v1.w); a1[7] += bfhi(v1.w);
            a2[0] += bflo(v2.x); a2[1] += bfhi(v2.x); a2[2] += bflo(v2.y); a2[3] += bfhi(v2.y);
            a2[4] += bflo(v2.z); a2[5] += bfhi(v2.z); a2[6] += bflo(v2.w); a2[7] += bfhi(v2.w);
            a3[0] += bflo(v3.x); a3[1] += bfhi(v3.x); a3[2] += bflo(v3.y); a3[3] += bfhi(v3.y);
            a3[4] += bflo(v3.z); a3[5] += bfhi(v3.z); a3[6] += bflo(v3.w); a3[7] += bfhi(v3.w);
        }
        for (; j < end; ++j) {
            const uint4 v = H4[(size_t)col[j] * 16 + sub];
            a0[0] += bflo(v.x); a0[1] += bfhi(v.x); a0[2] += bflo(v.y); a0[3] += bfhi(v.y);
            a0[4] += bflo(v.z); a0[5] += bfhi(v.z); a0[6] += bflo(v.w); a0[7] += bfhi(v.w);
        }
        const float dv = dinv[d];
        float r[8];
#pragma unroll
        for (int c = 0; c < 8; ++c) r[c] = ((a0[c] + a1[c]) + (a2[c] + a3[c])) * dv;
        uint4 o;
        o.x = packbf(r[0], r[1]); o.y = packbf(r[2], r[3]);
        o.z = packbf(r[4], r[5]); o.w = packbf(r[6], r[7]);
        out4[(size_t)d * 16 + sub] = o;
    }
}

// ---------------------------------------------------------------------------
// per-feature sum/sumsq from bf16 X; LDS pre-reduction then atomics
__global__ __launch_bounds__(256) void bn_reduce_bf(const u16* __restrict__ X,
                                                    float* __restrict__ sums, int n) {
    __shared__ float red[256];
    const int fp  = threadIdx.x & 63;   // feature-pair 0..63
    const int rof = threadIdx.x >> 6;   // 0..3
    const unsigned int* X2 = (const unsigned int*)X;
    float s0 = 0.f, q0 = 0.f, s1 = 0.f, q1 = 0.f;
    for (int r = blockIdx.x * 4 + rof; r < n; r += gridDim.x * 4) {
        unsigned int u = X2[(size_t)r * 64 + fp];
        float v0 = bflo(u), v1 = bfhi(u);
        s0 += v0; q0 += v0 * v0; s1 += v1; q1 += v1 * v1;
    }
    red[threadIdx.x] = s0; __syncthreads();
    if (rof == 0) s0 = red[fp] + red[fp + 64] + red[fp + 128] + red[fp + 192];
    __syncthreads(); red[threadIdx.x] = q0; __syncthreads();
    if (rof == 0) q0 = red[fp] + red[fp + 64] + red[fp + 128] + red[fp + 192];
    __syncthreads(); red[threadIdx.x] = s1; __syncthreads();
    if (rof == 0) s1 = red[fp] + red[fp + 64] + red[fp + 128] + red[fp + 192];
    __syncthreads(); red[threadIdx.x] = q1; __syncthreads();
    if (rof == 0) {
        q1 = red[fp] + red[fp + 64] + red[fp + 128] + red[fp + 192];
        int f = fp * 2;
        atomicAdd(&sums[f], s0);       atomicAdd(&sums[128 + f], q0);
        atomicAdd(&sums[f + 1], s1);   atomicAdd(&sums[128 + f + 1], q1);
    }
}

// ---------------------------------------------------------------------------
// BN + PReLU, bf16 in -> f32 out (final)
__global__ void bn_prelu_bf(const u16* __restrict__ X, const float* __restrict__ sums,
                            const float* __restrict__ gamma, const float* __restrict__ beta,
                            const float* __restrict__ a, float* __restrict__ out,
                            float invN) {
    int idx = blockIdx.x * blockDim.x + threadIdx.x;     // pair index
    if (idx >= N_NODES * 64) return;
    unsigned int u = ((const unsigned int*)X)[idx];
    int f0 = (idx * 2) & 127;
    float av = a[0];
    float2 o;
    {
        float mean = sums[f0] * invN;
        float var  = sums[128 + f0] * invN - mean * mean;
        float sc   = rsqrtf(var + BN_EPS) * gamma[f0];
        float y    = (bflo(u) - mean) * sc + beta[f0];
        o.x = (y >= 0.f) ? y : av * y;
    }
    {
        int f1 = f0 + 1;
        float mean = sums[f1] * invN;
        float var  = sums[128 + f1] * invN - mean * mean;
        float sc   = rsqrtf(var + BN_EPS) * gamma[f1];
        float y    = (bfhi(u) - mean) * sc + beta[f1];
        o.y = (y >= 0.f) ? y : av * y;
    }
    ((float2*)out)[idx] = o;
}

// ---------------------------------------------------------------------------
extern "C" void kernel_launch(void* const* d_in, const int* in_sizes, int n_in,
                              void* d_out, int out_size, void* d_ws, size_t ws_size,
                              hipStream_t stream) {
    const float* x      = (const float*)d_in[0];
    const int*   edges  = (const int*)d_in[1];   // [2, E]: src then dst
    const float* W1     = (const float*)d_in[2];
    // b1 = d_in[3] cancels under training-mode BN -> skipped
    const float* gamma1 = (const float*)d_in[4];
    const float* beta1  = (const float*)d_in[5];
    const float* a1     = (const float*)d_in[6];
    const float* W2     = (const float*)d_in[7];
    // b2 = d_in[8] skipped (same reason)
    const float* gamma2 = (const float*)d_in[9];
    const float* beta2  = (const float*)d_in[10];
    const float* a2     = (const float*)d_in[11];

    const int* src = edges;
    const int* dst = edges + N_EDGES;

    float* OUT = (float*)d_out;                      // final f32 output
    char* ws = (char*)d_ws;
    u16*   Abf      = (u16*)ws;    ws += (size_t)N_NODES * D * sizeof(u16);   // 12.8 MB
    u16*   Obf      = (u16*)ws;    ws += (size_t)N_NODES * D * sizeof(u16);   // 12.8 MB
    float* dinv     = (float*)ws;  ws += N_NODES * sizeof(float);
    float* sums     = (float*)ws;  ws += 512 * sizeof(float);   // [0..255]=L1, [256..511]=L2
    int*   row_ptr  = (int*)ws;    ws += (N_NODES + 1) * sizeof(int);
    int*   btot     = (int*)ws;    ws += NB * sizeof(int);
    int*   bbase    = (int*)ws;    ws += NB * sizeof(int);
    int*   bcur     = (int*)ws;    ws += NB * sizeof(int);
    int*   thist    = (int*)ws;    ws += (size_t)NTILES * 256 * sizeof(int);  // 200 KB
    unsigned int* brec = (unsigned int*)ws; ws += (size_t)N_EDGES * sizeof(unsigned int);
    u16*   col      = (u16*)ws;    ws += (size_t)N_EDGES * sizeof(u16);
    u16*   Wt1      = (u16*)ws;    ws += 16384 * sizeof(u16);
    u16*   Wt2      = (u16*)ws;    ws += 16384 * sizeof(u16);

    const float invN = 1.0f / (float)N_NODES;
    const int gemmGrid = (N_NODES + GEMM_ROWS - 1) / GEMM_ROWS;   // 391
    const int prGrid   = (N_NODES * 64 + 255) / 256;              // 12500

    // --- CSR build + weight prep + sums zero ---
    hist_prep<<<NTILES + 128, 256, 0, stream>>>(dst, W1, W2, thist, Wt1, Wt2, sums);
    bucket_scan<<<1, 256, 0, stream>>>(thist, btot, bbase, bcur, row_ptr);
    bucket_scatter<<<NTILES, 256, 0, stream>>>(src, dst, bcur, brec);
    bucket_csr<<<NB, 256, 0, stream>>>(brec, bbase, btot, row_ptr, col, dinv);

    // --- layer 1 ---
    gemm_bf16<false><<<gemmGrid, 256, 0, stream>>>(x, Wt1, Abf, dinv,
                                                   nullptr, nullptr, nullptr, nullptr, N_NODES);
    pull_agg<<<2048, 256, 0, stream>>>(Abf, row_ptr, col, dinv, Obf);
    bn_reduce_bf<<<512, 256, 0, stream>>>(Obf, sums, N_NODES);

    // --- layer 2 (BN1+PReLU fused into GEMM2 staging) ---
    gemm_bf16<true><<<gemmGrid, 256, 0, stream>>>(Obf, Wt2, Abf, dinv,
                                                  sums, gamma1, beta1, a1, N_NODES);
    pull_agg<<<2048, 256, 0, stream>>>(Abf, row_ptr, col, dinv, Obf);
    bn_reduce_bf<<<512, 256, 0, stream>>>(Obf, sums + 256, N_NODES);
    bn_prelu_bf<<<prGrid, 256, 0, stream>>>(Obf, sums + 256, gamma2, beta2, a2, OUT, invN);
}